// Round 8
// baseline (352.779 us; speedup 1.0000x reference)
//
#include <hip/hip_runtime.h>
#include <stdint.h>

// Problem constants
#define MM 4096   // B*S
#define SS 1024   // S
#define DD 1024   // D
#define HH 16     // heads
#define DKK 64    // head dim

typedef __bf16 bf16x8 __attribute__((ext_vector_type(8)));
typedef __bf16 bf16x4 __attribute__((ext_vector_type(4)));
typedef float  f32x4  __attribute__((ext_vector_type(4)));

#define LOG2E 1.44269504088896340736f

__device__ __forceinline__ void gload_lds16(const void* g, void* l) {
  // async global->LDS, 16B per lane; LDS dest is wave-uniform base + lane*16
  __builtin_amdgcn_global_load_lds(
      (__attribute__((address_space(1))) void*)g,
      (__attribute__((address_space(3))) void*)l, 16, 0, 0);
}

// Swizzled element offset within a [rows][64] bf16 tile (row = 128B = 8 chunks
// of 16B). chunk' = chunk ^ (row&7) -> conflict-free ds_read_b128 column reads.
#define LSW(row, ch) ((row) * 64 + ((((ch) ^ ((row) & 7)) << 3)))

// ---------------- pass 0+1: cvt (6144 blocks) + tiled wcombine (192) -------
// wcombine: Wc[z][h*64+j][i] = sum_d Wf_z[j][d] * W_z[h*64+d][i]
// tiled: block=(z,h,ic); thread owns col i, acc[64] over j; W read ONCE.
__global__ __launch_bounds__(256) void prep(
    const float* __restrict__ q, const float* __restrict__ k,
    const float* __restrict__ v,
    const float* __restrict__ Wq, const float* __restrict__ bq,
    const float* __restrict__ Wk, const float* __restrict__ bk,
    const float* __restrict__ Wv, const float* __restrict__ bv,
    const float* __restrict__ Wqf, const float* __restrict__ bqf,
    const float* __restrict__ Wkf, const float* __restrict__ bkf,
    const float* __restrict__ Wvf, const float* __restrict__ bvf,
    __bf16* __restrict__ X3, __bf16* __restrict__ Wc3,
    float* __restrict__ bc3) {
  int blk = blockIdx.x;
  if (blk < 6144) {
    int z = blk >> 11;          // 0,1,2
    int bx = blk & 2047;
    const float* src = (z == 0) ? q : ((z == 1) ? k : v);
    size_t i = ((size_t)bx * 256 + threadIdx.x) * 8;
    float4 a = *(const float4*)(src + i);
    float4 b = *(const float4*)(src + i + 4);
    bf16x8 r;
    r[0] = (__bf16)a.x; r[1] = (__bf16)a.y; r[2] = (__bf16)a.z; r[3] = (__bf16)a.w;
    r[4] = (__bf16)b.x; r[5] = (__bf16)b.y; r[6] = (__bf16)b.z; r[7] = (__bf16)b.w;
    *(bf16x8*)(X3 + (size_t)z * MM * DD + i) = r;
  } else {
    int t = blk - 6144;          // [0,192)
    int z = t >> 6;
    int rem = t & 63;
    int h = rem >> 2, ic = rem & 3;
    const float* W   = (z == 0) ? Wq  : ((z == 1) ? Wk  : Wv);
    const float* bs  = (z == 0) ? bq  : ((z == 1) ? bk  : bv);
    const float* Wf  = (z == 0) ? Wqf : ((z == 1) ? Wkf : Wvf);
    const float* bf_ = (z == 0) ? bqf : ((z == 1) ? bkf : bvf);
    int i = ic * 256 + threadIdx.x;

    float acc[64];
#pragma unroll
    for (int j = 0; j < 64; ++j) acc[j] = 0.f;
#pragma unroll 4
    for (int d = 0; d < 64; ++d) {
      float wv = W[(size_t)(h * DKK + d) * DD + i];
#pragma unroll
      for (int j = 0; j < 64; ++j)
        acc[j] = fmaf(Wf[j * DKK + d], wv, acc[j]);  // Wf idx uniform -> s_load
    }
#pragma unroll 8
    for (int j = 0; j < 64; ++j)
      Wc3[(size_t)z * DD * DD + (size_t)(h * DKK + j) * DD + i] = (__bf16)acc[j];

    if (ic == 0 && threadIdx.x < 64) {
      int j = threadIdx.x;
      float bb = bf_[j];
      for (int d = 0; d < 64; ++d) bb += Wf[j * DKK + d] * bs[h * DKK + d];
      bc3[z * DD + h * DKK + j] = bb;
    }
  }
}

// ---------------- pass 2: fused 3x GEMM+bias+ReLU, C = relu(X@Wc^T + bc) ---
// z=0: Q rows [m][o];  z=1: K rows [m][o];  z=2: V stored TRANSPOSED
// per head: Vt[(bh*64+dk)*1024 + s]  (so attention PV reads are contiguous)
__global__ __launch_bounds__(256) void gemm3(const __bf16* __restrict__ X3,
                                             const __bf16* __restrict__ Wc3,
                                             const float* __restrict__ bc3,
                                             __bf16* __restrict__ QKV) {
  __shared__ __bf16 As[128 * 64];
  __shared__ __bf16 Bs[128 * 64];
  const int z = blockIdx.z;
  const __bf16* A  = X3  + (size_t)z * MM * DD;
  const __bf16* Bt = Wc3 + (size_t)z * DD * DD;
  const float* bias = bc3 + z * DD;
  __bf16* C = QKV + (size_t)z * MM * DD;

  const int tid = threadIdx.x;
  const int wave = tid >> 6, lane = tid & 63;
  const int l15 = lane & 15, l4 = lane >> 4;
  const int bm = blockIdx.x * 128;
  const int bn = blockIdx.y * 128;
  const int wr = (wave >> 1) * 64;
  const int wc = (wave & 1) * 64;

  f32x4 acc[4][4] = {};

  const int srow = wave * 8 + (lane >> 3);  // staging row within 32-row issue
  const int scol = (lane & 7) * 8;

  for (int kt = 0; kt < DD; kt += 64) {
    __syncthreads();
#pragma unroll
    for (int j = 0; j < 4; ++j) {
      int row = j * 32 + srow;
      gload_lds16(A  + (size_t)(bm + row) * DD + kt + scol, As + j * 2048 + wave * 512);
      gload_lds16(Bt + (size_t)(bn + row) * DD + kt + scol, Bs + j * 2048 + wave * 512);
    }
    asm volatile("s_waitcnt vmcnt(0)" ::: "memory");
    __syncthreads();
#pragma unroll
    for (int ks = 0; ks < 2; ++ks) {
      bf16x8 af[4], bfr[4];
#pragma unroll
      for (int mi = 0; mi < 4; ++mi)
        af[mi] = *(const bf16x8*)(As + (wr + mi * 16 + l15) * 64 + ks * 32 + l4 * 8);
#pragma unroll
      for (int ni = 0; ni < 4; ++ni)
        bfr[ni] = *(const bf16x8*)(Bs + (wc + ni * 16 + l15) * 64 + ks * 32 + l4 * 8);
#pragma unroll
      for (int mi = 0; mi < 4; ++mi)
#pragma unroll
        for (int ni = 0; ni < 4; ++ni)
          acc[mi][ni] = __builtin_amdgcn_mfma_f32_16x16x32_bf16(af[mi], bfr[ni], acc[mi][ni], 0, 0, 0);
    }
  }

  // epilogue: bias + relu + bf16 store (z==2 -> transposed per-head layout)
#pragma unroll
  for (int ni = 0; ni < 4; ++ni) {
    int n = bn + wc + ni * 16 + l15;
    float bb = bias[n];
#pragma unroll
    for (int mi = 0; mi < 4; ++mi) {
      if (z != 2) {
#pragma unroll
        for (int r = 0; r < 4; ++r) {
          int m = bm + wr + mi * 16 + l4 * 4 + r;
          float vv = acc[mi][ni][r] + bb;
          vv = vv > 0.f ? vv : 0.f;
          C[(size_t)m * DD + n] = (__bf16)vv;
        }
      } else {
        int m0 = bm + wr + mi * 16 + l4 * 4;
        int b = m0 >> 10, s0 = m0 & 1023;
        int h = n >> 6, dk = n & 63;
        bf16x4 pk;
#pragma unroll
        for (int r = 0; r < 4; ++r) {
          float vv = acc[mi][ni][r] + bb;
          vv = vv > 0.f ? vv : 0.f;
          pk[r] = (__bf16)vv;
        }
        *(bf16x4*)(C + ((size_t)(b * HH + h) * DKK + dk) * SS + s0) = pk;
      }
    }
  }
}

// ---------------- pass 3: flash attention + fused Wo epilogue --------------
// 512 blocks (8 qt x 64 bh), XCD-swizzled. 8 waves, 128 q rows per block.
// K/V double-buffered, 2-phase: issue kt+1 loads, compute kt, one
// vmcnt(0)+barrier per iter (stage latency hidden under compute).
__global__ __launch_bounds__(512) void attn_kernel(
    const __bf16* __restrict__ Q,   // [4096][1024]
    const __bf16* __restrict__ K,   // [4096][1024]
    const __bf16* __restrict__ Vt,  // [64 bh][64 dk][1024 s]
    const int* __restrict__ mask,   // [64][1024]
    const float* __restrict__ Wo,   // [64][64]
    const float* __restrict__ bo,   // [64]
    float* __restrict__ out)        // [4][1024][1024]
{
  __shared__ __bf16 Qs[128 * 64];     // 16KB
  __shared__ __bf16 Ks[2][64 * 64];   // 16KB (double-buffered)
  __shared__ __bf16 Vs[2][64 * 64];   // 16KB
  __shared__ __bf16 Pw[8][16 * 64];   // 16KB per-wave P staging
  __shared__ __bf16 Wos[64 * 64];     // 8KB   -> 72KB total, 2 blocks/CU

  const int tid = threadIdx.x;
  const int wave = tid >> 6, lane = tid & 63;
  const int l15 = lane & 15, l4 = lane >> 4;

  // T1: XCD remap. 512 blocks: XCD c gets bh [c*8,c*8+8) x all 8 qt.
  const int lin = blockIdx.x;
  const int swz = (lin & 7) * 64 + (lin >> 3);
  const int qt = swz & 7;
  const int bh = swz >> 3;
  const int b = bh >> 4, h = bh & 15;

  const __bf16* Qbase = Q + ((size_t)b * SS + qt * 128) * DD + h * 64;
  const __bf16* Kbase = K + (size_t)b * SS * DD + h * 64;
  const __bf16* Vbase = Vt + (size_t)bh * DKK * SS;

  // stage Wo -> LDS bf16, swizzled store
  for (int t = tid; t < 64 * 64; t += 512) {
    int row = t >> 6, col = t & 63;
    Wos[row * 64 + ((((col >> 3) ^ (row & 7)) << 3) | (col & 7))] = (__bf16)Wo[t];
  }

  // staging map: lane l covers chunk (l&7) of row (..+ l>>3); row&7 == l>>3,
  // so pre-swizzled global chunk = (l&7)^(l>>3).   (rule #21: LDS stays linear)
  const int lr8 = lane >> 3;
  const int scol = (((lane & 7) ^ lr8) * 8);
  const int krow = wave * 8 + lr8;           // K/V stage row (64-row tile)

  // stage Q tile (128 rows): wave stages rows [wave*16, wave*16+16)
#pragma unroll
  for (int j = 0; j < 2; ++j)
    gload_lds16(Qbase + (size_t)(wave * 16 + j * 8 + lr8) * DD + scol,
                Qs + wave * 1024 + j * 512);
  // stage K/V tile 0 into buf 0
  gload_lds16(Kbase + (size_t)krow * DD + scol, Ks[0] + wave * 512);
  gload_lds16(Vbase + (size_t)krow * SS + scol, Vs[0] + wave * 512);
  asm volatile("s_waitcnt vmcnt(0)" ::: "memory");
  __syncthreads();

  f32x4 o_acc[4] = {};
  float mrow[4], lrow[4];
#pragma unroll
  for (int r = 0; r < 4; ++r) { mrow[r] = -1e30f; lrow[r] = 0.f; }

  // exp2-domain softmax: t = score*0.125*log2e; masked -> -10000*log2e
  const float SCL = 0.125f * LOG2E;

  for (int kt = 0; kt < SS / 64; ++kt) {
    const int cur = kt & 1;
    if (kt < SS / 64 - 1) {  // prefetch next K/V tile into other buffer
      gload_lds16(Kbase + (size_t)((kt + 1) * 64 + krow) * DD + scol,
                  Ks[cur ^ 1] + wave * 512);
      gload_lds16(Vbase + (size_t)krow * SS + (kt + 1) * 64 + scol,
                  Vs[cur ^ 1] + wave * 512);
    }

    // S = Q K^T for this wave's 16 q rows x 64 keys
    f32x4 sc[4] = {};
#pragma unroll
    for (int ks = 0; ks < 2; ++ks) {
      bf16x8 aq = *(const bf16x8*)(Qs + LSW(wave * 16 + l15, ks * 4 + l4));
#pragma unroll
      for (int ni = 0; ni < 4; ++ni) {
        bf16x8 kf = *(const bf16x8*)(Ks[cur] + LSW(ni * 16 + l15, ks * 4 + l4));
        sc[ni] = __builtin_amdgcn_mfma_f32_16x16x32_bf16(aq, kf, sc[ni], 0, 0, 0);
      }
    }
    // scale into exp2 domain + mask (replace with -10000, per reference)
#pragma unroll
    for (int ni = 0; ni < 4; ++ni) {
      int key = kt * 64 + ni * 16 + l15;
      int mv = mask[bh * SS + key];
#pragma unroll
      for (int r = 0; r < 4; ++r) {
        float s = sc[ni][r] * SCL;
        sc[ni][r] = (mv == 0) ? (-10000.f * LOG2E) : s;
      }
    }
    // online softmax (16-lane row reduce, exp2 domain)
    float alpha[4];
#pragma unroll
    for (int r = 0; r < 4; ++r) {
      float v = fmaxf(fmaxf(sc[0][r], sc[1][r]), fmaxf(sc[2][r], sc[3][r]));
      v = fmaxf(v, __shfl_xor(v, 1));
      v = fmaxf(v, __shfl_xor(v, 2));
      v = fmaxf(v, __shfl_xor(v, 4));
      v = fmaxf(v, __shfl_xor(v, 8));
      float mnew = fmaxf(mrow[r], v);
      alpha[r] = __builtin_exp2f(mrow[r] - mnew);
      mrow[r] = mnew;
      float s = 0.f;
#pragma unroll
      for (int ni = 0; ni < 4; ++ni) {
        float p = __builtin_exp2f(sc[ni][r] - mnew);
        sc[ni][r] = p;
        s += p;
      }
      s += __shfl_xor(s, 1); s += __shfl_xor(s, 2);
      s += __shfl_xor(s, 4); s += __shfl_xor(s, 8);
      lrow[r] = lrow[r] * alpha[r] + s;
    }
    // P -> per-wave LDS (swizzled scatter)
#pragma unroll
    for (int ni = 0; ni < 4; ++ni)
#pragma unroll
      for (int r = 0; r < 4; ++r) {
        int row = l4 * 4 + r;
        int ch = 2 * ni + (l15 >> 3);
        Pw[wave][row * 64 + (((ch ^ (row & 7)) << 3) | (l15 & 7))] = (__bf16)sc[ni][r];
      }
    asm volatile("" ::: "memory");
    // rescale O
#pragma unroll
    for (int ni = 0; ni < 4; ++ni)
#pragma unroll
      for (int r = 0; r < 4; ++r) o_acc[ni][r] *= alpha[r];
    // O += P V
#pragma unroll
    for (int ks = 0; ks < 2; ++ks) {
      bf16x8 ap = *(const bf16x8*)(&Pw[wave][LSW(l15, ks * 4 + l4)]);
#pragma unroll
      for (int ni = 0; ni < 4; ++ni) {
        bf16x8 vf = *(const bf16x8*)(Vs[cur] + LSW(ni * 16 + l15, ks * 4 + l4));
        o_acc[ni] = __builtin_amdgcn_mfma_f32_16x16x32_bf16(ap, vf, o_acc[ni], 0, 0, 0);
      }
    }
    // drain prefetch + protect buf cur (overwritten next iter)
    asm volatile("s_waitcnt vmcnt(0)" ::: "memory");
    __syncthreads();
  }

  // normalize, then fused per-head Wo: final = (O/l) @ Wo^T + bo
#pragma unroll
  for (int ni = 0; ni < 4; ++ni)
#pragma unroll
    for (int r = 0; r < 4; ++r) {
      int row = l4 * 4 + r;
      int ch = 2 * ni + (l15 >> 3);
      Pw[wave][row * 64 + (((ch ^ (row & 7)) << 3) | (l15 & 7))] =
          (__bf16)(o_acc[ni][r] / lrow[r]);
    }
  asm volatile("" ::: "memory");
  f32x4 facc[4] = {};
#pragma unroll
  for (int ks = 0; ks < 2; ++ks) {
    bf16x8 ao = *(const bf16x8*)(&Pw[wave][LSW(l15, ks * 4 + l4)]);
#pragma unroll
    for (int ni = 0; ni < 4; ++ni) {
      bf16x8 wf = *(const bf16x8*)(Wos + LSW(ni * 16 + l15, ks * 4 + l4));
      facc[ni] = __builtin_amdgcn_mfma_f32_16x16x32_bf16(ao, wf, facc[ni], 0, 0, 0);
    }
  }
#pragma unroll
  for (int ni = 0; ni < 4; ++ni) {
    int j = ni * 16 + l15;
    float bb = bo[j];
#pragma unroll
    for (int r = 0; r < 4; ++r) {
      int qrow = qt * 128 + wave * 16 + l4 * 4 + r;
      out[((size_t)b * SS + qrow) * DD + h * 64 + j] = facc[ni][r] + bb;
    }
  }
}

// ---------------- host ----------------
extern "C" void kernel_launch(void* const* d_in, const int* in_sizes, int n_in,
                              void* d_out, int out_size, void* d_ws, size_t ws_size,
                              hipStream_t stream) {
  const float* q   = (const float*)d_in[0];
  const float* k   = (const float*)d_in[1];
  const float* v   = (const float*)d_in[2];
  const int*   mask= (const int*)d_in[3];
  const float* Wq  = (const float*)d_in[4];
  const float* bq  = (const float*)d_in[5];
  const float* Wk  = (const float*)d_in[6];
  const float* bk  = (const float*)d_in[7];
  const float* Wv  = (const float*)d_in[8];
  const float* bv  = (const float*)d_in[9];
  const float* Wqf = (const float*)d_in[10];
  const float* bqf = (const float*)d_in[11];
  const float* Wkf = (const float*)d_in[12];
  const float* bkf = (const float*)d_in[13];
  const float* Wvf = (const float*)d_in[14];
  const float* bvf = (const float*)d_in[15];
  const float* Wo  = (const float*)d_in[16];
  const float* bo  = (const float*)d_in[17];
  float* out = (float*)d_out;

  // workspace layout
  char* p = (char*)d_ws;
  __bf16* X3  = (__bf16*)p; p += (size_t)3 * MM * DD * 2;   // 24 MB
  __bf16* Wc3 = (__bf16*)p; p += (size_t)3 * DD * DD * 2;   // 6 MB
  __bf16* QKV = (__bf16*)p; p += (size_t)3 * MM * DD * 2;   // 24 MB
  float*  bc3 = (float*)p;  p += (size_t)3 * DD * 4;        // 12 KB
  if ((size_t)(p - (char*)d_ws) > ws_size) return;  // workspace too small

  prep<<<6336, 256, 0, stream>>>(q, k, v, Wq, bq, Wk, bk, Wv, bv,
                                 Wqf, bqf, Wkf, bkf, Wvf, bvf, X3, Wc3, bc3);
  gemm3<<<dim3(32, 8, 3), 256, 0, stream>>>(X3, Wc3, bc3, QKV);
  attn_kernel<<<512, 512, 0, stream>>>(
      QKV, QKV + (size_t)MM * DD, QKV + (size_t)2 * MM * DD, mask, Wo, bo, out);
}

// Round 9
// 245.457 us; speedup vs baseline: 1.4372x; 1.4372x over previous
//
#include <hip/hip_runtime.h>
#include <stdint.h>

// Problem constants
#define MM 4096   // B*S
#define SS 1024   // S
#define DD 1024   // D
#define HH 16     // heads
#define DKK 64    // head dim

typedef __bf16 bf16x8 __attribute__((ext_vector_type(8)));
typedef __bf16 bf16x4 __attribute__((ext_vector_type(4)));
typedef float  f32x4  __attribute__((ext_vector_type(4)));

#define LOG2E 1.44269504088896340736f

__device__ __forceinline__ void gload_lds16(const void* g, void* l) {
  // async global->LDS, 16B per lane; LDS dest is wave-uniform base + lane*16
  __builtin_amdgcn_global_load_lds(
      (__attribute__((address_space(1))) void*)g,
      (__attribute__((address_space(3))) void*)l, 16, 0, 0);
}

// Swizzled element offset within a [rows][64] bf16 tile (row = 128B = 8 chunks
// of 16B). chunk' = chunk ^ (row&7) -> conflict-free ds_read_b128 column reads.
#define LSW(row, ch) ((row) * 64 + ((((ch) ^ ((row) & 7)) << 3)))

// ---------------- pass 0+1: cvt (6144 blocks) + wcombine (768 blocks) ------
// wcombine: Wc[z][h*64+j][i] = sum_d Wf_z[j][d] * W_z[h*64+d][i]
// block=(z,h,ic,jc): thread owns col i, acc[16] over j in [jc*16,jc*16+16).
// ALL acc loops fully unrolled -> static indices -> registers (rule #20).
__global__ __launch_bounds__(256) void prep(
    const float* __restrict__ q, const float* __restrict__ k,
    const float* __restrict__ v,
    const float* __restrict__ Wq, const float* __restrict__ bq,
    const float* __restrict__ Wk, const float* __restrict__ bk,
    const float* __restrict__ Wv, const float* __restrict__ bv,
    const float* __restrict__ Wqf, const float* __restrict__ bqf,
    const float* __restrict__ Wkf, const float* __restrict__ bkf,
    const float* __restrict__ Wvf, const float* __restrict__ bvf,
    __bf16* __restrict__ X3, __bf16* __restrict__ Wc3,
    float* __restrict__ bc3) {
  int blk = blockIdx.x;
  if (blk < 6144) {
    int z = blk >> 11;          // 0,1,2
    int bx = blk & 2047;
    const float* src = (z == 0) ? q : ((z == 1) ? k : v);
    size_t i = ((size_t)bx * 256 + threadIdx.x) * 8;
    float4 a = *(const float4*)(src + i);
    float4 b = *(const float4*)(src + i + 4);
    bf16x8 r;
    r[0] = (__bf16)a.x; r[1] = (__bf16)a.y; r[2] = (__bf16)a.z; r[3] = (__bf16)a.w;
    r[4] = (__bf16)b.x; r[5] = (__bf16)b.y; r[6] = (__bf16)b.z; r[7] = (__bf16)b.w;
    *(bf16x8*)(X3 + (size_t)z * MM * DD + i) = r;
  } else {
    int t = blk - 6144;          // [0,768): z(3) x h(16) x ic(4) x jc(4)
    int z = t >> 8;              // t/256
    int rem = t & 255;
    int h = rem >> 4, ic = (rem >> 2) & 3, jc = rem & 3;
    const float* W   = (z == 0) ? Wq  : ((z == 1) ? Wk  : Wv);
    const float* bs  = (z == 0) ? bq  : ((z == 1) ? bk  : bv);
    const float* Wf  = (z == 0) ? Wqf : ((z == 1) ? Wkf : Wvf);
    const float* bf_ = (z == 0) ? bqf : ((z == 1) ? bkf : bvf);
    int i = ic * 256 + threadIdx.x;
    const float* wfb = Wf + jc * 16 * DKK;   // 16 rows of Wf

    float acc[16];
#pragma unroll
    for (int jj = 0; jj < 16; ++jj) acc[jj] = 0.f;
#pragma unroll 4
    for (int d = 0; d < 64; ++d) {
      float wv = W[(size_t)(h * DKK + d) * DD + i];
#pragma unroll
      for (int jj = 0; jj < 16; ++jj)
        acc[jj] = fmaf(wfb[jj * DKK + d], wv, acc[jj]);  // uniform -> s_load
    }
#pragma unroll
    for (int jj = 0; jj < 16; ++jj)
      Wc3[(size_t)z * DD * DD + (size_t)(h * DKK + jc * 16 + jj) * DD + i] =
          (__bf16)acc[jj];

    if (ic == 0 && jc == 0 && threadIdx.x < 64) {
      int j = threadIdx.x;
      float bb = bf_[j];
      for (int d = 0; d < 64; ++d) bb += Wf[j * DKK + d] * bs[h * DKK + d];
      bc3[z * DD + h * DKK + j] = bb;
    }
  }
}

// ---------------- pass 2: fused 3x GEMM+bias+ReLU, C = relu(X@Wc^T + bc) ---
// z=0: Q rows [m][o];  z=1: K rows [m][o];  z=2: V stored TRANSPOSED
// per head: Vt[(bh*64+dk)*1024 + s]  (so attention PV reads are contiguous)
__global__ __launch_bounds__(256) void gemm3(const __bf16* __restrict__ X3,
                                             const __bf16* __restrict__ Wc3,
                                             const float* __restrict__ bc3,
                                             __bf16* __restrict__ QKV) {
  __shared__ __bf16 As[128 * 64];
  __shared__ __bf16 Bs[128 * 64];
  const int z = blockIdx.z;
  const __bf16* A  = X3  + (size_t)z * MM * DD;
  const __bf16* Bt = Wc3 + (size_t)z * DD * DD;
  const float* bias = bc3 + z * DD;
  __bf16* C = QKV + (size_t)z * MM * DD;

  const int tid = threadIdx.x;
  const int wave = tid >> 6, lane = tid & 63;
  const int l15 = lane & 15, l4 = lane >> 4;
  const int bm = blockIdx.x * 128;
  const int bn = blockIdx.y * 128;
  const int wr = (wave >> 1) * 64;
  const int wc = (wave & 1) * 64;

  f32x4 acc[4][4] = {};

  const int srow = wave * 8 + (lane >> 3);  // staging row within 32-row issue
  const int scol = (lane & 7) * 8;

  for (int kt = 0; kt < DD; kt += 64) {
    __syncthreads();
#pragma unroll
    for (int j = 0; j < 4; ++j) {
      int row = j * 32 + srow;
      gload_lds16(A  + (size_t)(bm + row) * DD + kt + scol, As + j * 2048 + wave * 512);
      gload_lds16(Bt + (size_t)(bn + row) * DD + kt + scol, Bs + j * 2048 + wave * 512);
    }
    asm volatile("s_waitcnt vmcnt(0)" ::: "memory");
    __syncthreads();
#pragma unroll
    for (int ks = 0; ks < 2; ++ks) {
      bf16x8 af[4], bfr[4];
#pragma unroll
      for (int mi = 0; mi < 4; ++mi)
        af[mi] = *(const bf16x8*)(As + (wr + mi * 16 + l15) * 64 + ks * 32 + l4 * 8);
#pragma unroll
      for (int ni = 0; ni < 4; ++ni)
        bfr[ni] = *(const bf16x8*)(Bs + (wc + ni * 16 + l15) * 64 + ks * 32 + l4 * 8);
#pragma unroll
      for (int mi = 0; mi < 4; ++mi)
#pragma unroll
        for (int ni = 0; ni < 4; ++ni)
          acc[mi][ni] = __builtin_amdgcn_mfma_f32_16x16x32_bf16(af[mi], bfr[ni], acc[mi][ni], 0, 0, 0);
    }
  }

  // epilogue: bias + relu + bf16 store (z==2 -> transposed per-head layout)
#pragma unroll
  for (int ni = 0; ni < 4; ++ni) {
    int n = bn + wc + ni * 16 + l15;
    float bb = bias[n];
#pragma unroll
    for (int mi = 0; mi < 4; ++mi) {
      if (z != 2) {
#pragma unroll
        for (int r = 0; r < 4; ++r) {
          int m = bm + wr + mi * 16 + l4 * 4 + r;
          float vv = acc[mi][ni][r] + bb;
          vv = vv > 0.f ? vv : 0.f;
          C[(size_t)m * DD + n] = (__bf16)vv;
        }
      } else {
        int m0 = bm + wr + mi * 16 + l4 * 4;
        int b = m0 >> 10, s0 = m0 & 1023;
        int h = n >> 6, dk = n & 63;
        bf16x4 pk;
#pragma unroll
        for (int r = 0; r < 4; ++r) {
          float vv = acc[mi][ni][r] + bb;
          vv = vv > 0.f ? vv : 0.f;
          pk[r] = (__bf16)vv;
        }
        *(bf16x4*)(C + ((size_t)(b * HH + h) * DKK + dk) * SS + s0) = pk;
      }
    }
  }
}

// ---------------- pass 3: flash attention + fused Wo epilogue --------------
// 512 blocks (8 qt x 64 bh), XCD-swizzled. 8 waves, 128 q rows per block.
// K/V double-buffered, 2-phase: issue kt+1 loads, compute kt, one
// vmcnt(0)+barrier per iter (stage latency hidden under compute).
__global__ __launch_bounds__(512) void attn_kernel(
    const __bf16* __restrict__ Q,   // [4096][1024]
    const __bf16* __restrict__ K,   // [4096][1024]
    const __bf16* __restrict__ Vt,  // [64 bh][64 dk][1024 s]
    const int* __restrict__ mask,   // [64][1024]
    const float* __restrict__ Wo,   // [64][64]
    const float* __restrict__ bo,   // [64]
    float* __restrict__ out)        // [4][1024][1024]
{
  __shared__ __bf16 Qs[128 * 64];     // 16KB
  __shared__ __bf16 Ks[2][64 * 64];   // 16KB (double-buffered)
  __shared__ __bf16 Vs[2][64 * 64];   // 16KB
  __shared__ __bf16 Pw[8][16 * 64];   // 16KB per-wave P staging
  __shared__ __bf16 Wos[64 * 64];     // 8KB   -> 72KB total, 2 blocks/CU

  const int tid = threadIdx.x;
  const int wave = tid >> 6, lane = tid & 63;
  const int l15 = lane & 15, l4 = lane >> 4;

  // T1: XCD remap. 512 blocks: XCD c gets bh [c*8,c*8+8) x all 8 qt.
  const int lin = blockIdx.x;
  const int swz = (lin & 7) * 64 + (lin >> 3);
  const int qt = swz & 7;
  const int bh = swz >> 3;
  const int b = bh >> 4, h = bh & 15;

  const __bf16* Qbase = Q + ((size_t)b * SS + qt * 128) * DD + h * 64;
  const __bf16* Kbase = K + (size_t)b * SS * DD + h * 64;
  const __bf16* Vbase = Vt + (size_t)bh * DKK * SS;

  // stage Wo -> LDS bf16, swizzled store
  for (int t = tid; t < 64 * 64; t += 512) {
    int row = t >> 6, col = t & 63;
    Wos[row * 64 + ((((col >> 3) ^ (row & 7)) << 3) | (col & 7))] = (__bf16)Wo[t];
  }

  // staging map: lane l covers chunk (l&7) of row (..+ l>>3); row&7 == l>>3,
  // so pre-swizzled global chunk = (l&7)^(l>>3).   (rule #21: LDS stays linear)
  const int lr8 = lane >> 3;
  const int scol = (((lane & 7) ^ lr8) * 8);
  const int krow = wave * 8 + lr8;           // K/V stage row (64-row tile)

  // stage Q tile (128 rows): wave stages rows [wave*16, wave*16+16)
#pragma unroll
  for (int j = 0; j < 2; ++j)
    gload_lds16(Qbase + (size_t)(wave * 16 + j * 8 + lr8) * DD + scol,
                Qs + wave * 1024 + j * 512);
  // stage K/V tile 0 into buf 0
  gload_lds16(Kbase + (size_t)krow * DD + scol, Ks[0] + wave * 512);
  gload_lds16(Vbase + (size_t)krow * SS + scol, Vs[0] + wave * 512);
  asm volatile("s_waitcnt vmcnt(0)" ::: "memory");
  __syncthreads();

  f32x4 o_acc[4] = {};
  float mrow[4], lrow[4];
#pragma unroll
  for (int r = 0; r < 4; ++r) { mrow[r] = -1e30f; lrow[r] = 0.f; }

  // exp2-domain softmax: t = score*0.125*log2e; masked -> -10000*log2e
  const float SCL = 0.125f * LOG2E;

  for (int kt = 0; kt < SS / 64; ++kt) {
    const int cur = kt & 1;
    if (kt < SS / 64 - 1) {  // prefetch next K/V tile into other buffer
      gload_lds16(Kbase + (size_t)((kt + 1) * 64 + krow) * DD + scol,
                  Ks[cur ^ 1] + wave * 512);
      gload_lds16(Vbase + (size_t)krow * SS + (kt + 1) * 64 + scol,
                  Vs[cur ^ 1] + wave * 512);
    }

    // S = Q K^T for this wave's 16 q rows x 64 keys
    f32x4 sc[4] = {};
#pragma unroll
    for (int ks = 0; ks < 2; ++ks) {
      bf16x8 aq = *(const bf16x8*)(Qs + LSW(wave * 16 + l15, ks * 4 + l4));
#pragma unroll
      for (int ni = 0; ni < 4; ++ni) {
        bf16x8 kf = *(const bf16x8*)(Ks[cur] + LSW(ni * 16 + l15, ks * 4 + l4));
        sc[ni] = __builtin_amdgcn_mfma_f32_16x16x32_bf16(aq, kf, sc[ni], 0, 0, 0);
      }
    }
    // scale into exp2 domain + mask (replace with -10000, per reference)
#pragma unroll
    for (int ni = 0; ni < 4; ++ni) {
      int key = kt * 64 + ni * 16 + l15;
      int mv = mask[bh * SS + key];
#pragma unroll
      for (int r = 0; r < 4; ++r) {
        float s = sc[ni][r] * SCL;
        sc[ni][r] = (mv == 0) ? (-10000.f * LOG2E) : s;
      }
    }
    // online softmax (16-lane row reduce, exp2 domain)
    float alpha[4];
#pragma unroll
    for (int r = 0; r < 4; ++r) {
      float v = fmaxf(fmaxf(sc[0][r], sc[1][r]), fmaxf(sc[2][r], sc[3][r]));
      v = fmaxf(v, __shfl_xor(v, 1));
      v = fmaxf(v, __shfl_xor(v, 2));
      v = fmaxf(v, __shfl_xor(v, 4));
      v = fmaxf(v, __shfl_xor(v, 8));
      float mnew = fmaxf(mrow[r], v);
      alpha[r] = __builtin_exp2f(mrow[r] - mnew);
      mrow[r] = mnew;
      float s = 0.f;
#pragma unroll
      for (int ni = 0; ni < 4; ++ni) {
        float p = __builtin_exp2f(sc[ni][r] - mnew);
        sc[ni][r] = p;
        s += p;
      }
      s += __shfl_xor(s, 1); s += __shfl_xor(s, 2);
      s += __shfl_xor(s, 4); s += __shfl_xor(s, 8);
      lrow[r] = lrow[r] * alpha[r] + s;
    }
    // P -> per-wave LDS (swizzled scatter)
#pragma unroll
    for (int ni = 0; ni < 4; ++ni)
#pragma unroll
      for (int r = 0; r < 4; ++r) {
        int row = l4 * 4 + r;
        int ch = 2 * ni + (l15 >> 3);
        Pw[wave][row * 64 + (((ch ^ (row & 7)) << 3) | (l15 & 7))] = (__bf16)sc[ni][r];
      }
    asm volatile("" ::: "memory");
    // rescale O
#pragma unroll
    for (int ni = 0; ni < 4; ++ni)
#pragma unroll
      for (int r = 0; r < 4; ++r) o_acc[ni][r] *= alpha[r];
    // O += P V
#pragma unroll
    for (int ks = 0; ks < 2; ++ks) {
      bf16x8 ap = *(const bf16x8*)(&Pw[wave][LSW(l15, ks * 4 + l4)]);
#pragma unroll
      for (int ni = 0; ni < 4; ++ni) {
        bf16x8 vf = *(const bf16x8*)(Vs[cur] + LSW(ni * 16 + l15, ks * 4 + l4));
        o_acc[ni] = __builtin_amdgcn_mfma_f32_16x16x32_bf16(ap, vf, o_acc[ni], 0, 0, 0);
      }
    }
    // drain prefetch + protect buf cur (overwritten next iter)
    asm volatile("s_waitcnt vmcnt(0)" ::: "memory");
    __syncthreads();
  }

  // normalize, then fused per-head Wo: final = (O/l) @ Wo^T + bo
#pragma unroll
  for (int ni = 0; ni < 4; ++ni)
#pragma unroll
    for (int r = 0; r < 4; ++r) {
      int row = l4 * 4 + r;
      int ch = 2 * ni + (l15 >> 3);
      Pw[wave][row * 64 + (((ch ^ (row & 7)) << 3) | (l15 & 7))] =
          (__bf16)(o_acc[ni][r] / lrow[r]);
    }
  asm volatile("" ::: "memory");
  f32x4 facc[4] = {};
#pragma unroll
  for (int ks = 0; ks < 2; ++ks) {
    bf16x8 ao = *(const bf16x8*)(&Pw[wave][LSW(l15, ks * 4 + l4)]);
#pragma unroll
    for (int ni = 0; ni < 4; ++ni) {
      bf16x8 wf = *(const bf16x8*)(Wos + LSW(ni * 16 + l15, ks * 4 + l4));
      facc[ni] = __builtin_amdgcn_mfma_f32_16x16x32_bf16(ao, wf, facc[ni], 0, 0, 0);
    }
  }
#pragma unroll
  for (int ni = 0; ni < 4; ++ni) {
    int j = ni * 16 + l15;
    float bb = bo[j];
#pragma unroll
    for (int r = 0; r < 4; ++r) {
      int qrow = qt * 128 + wave * 16 + l4 * 4 + r;
      out[((size_t)b * SS + qrow) * DD + h * 64 + j] = facc[ni][r] + bb;
    }
  }
}

// ---------------- host ----------------
extern "C" void kernel_launch(void* const* d_in, const int* in_sizes, int n_in,
                              void* d_out, int out_size, void* d_ws, size_t ws_size,
                              hipStream_t stream) {
  const float* q   = (const float*)d_in[0];
  const float* k   = (const float*)d_in[1];
  const float* v   = (const float*)d_in[2];
  const int*   mask= (const int*)d_in[3];
  const float* Wq  = (const float*)d_in[4];
  const float* bq  = (const float*)d_in[5];
  const float* Wk  = (const float*)d_in[6];
  const float* bk  = (const float*)d_in[7];
  const float* Wv  = (const float*)d_in[8];
  const float* bv  = (const float*)d_in[9];
  const float* Wqf = (const float*)d_in[10];
  const float* bqf = (const float*)d_in[11];
  const float* Wkf = (const float*)d_in[12];
  const float* bkf = (const float*)d_in[13];
  const float* Wvf = (const float*)d_in[14];
  const float* bvf = (const float*)d_in[15];
  const float* Wo  = (const float*)d_in[16];
  const float* bo  = (const float*)d_in[17];
  float* out = (float*)d_out;

  // workspace layout
  char* p = (char*)d_ws;
  __bf16* X3  = (__bf16*)p; p += (size_t)3 * MM * DD * 2;   // 24 MB
  __bf16* Wc3 = (__bf16*)p; p += (size_t)3 * DD * DD * 2;   // 6 MB
  __bf16* QKV = (__bf16*)p; p += (size_t)3 * MM * DD * 2;   // 24 MB
  float*  bc3 = (float*)p;  p += (size_t)3 * DD * 4;        // 12 KB
  if ((size_t)(p - (char*)d_ws) > ws_size) return;  // workspace too small

  prep<<<6912, 256, 0, stream>>>(q, k, v, Wq, bq, Wk, bk, Wv, bv,
                                 Wqf, bqf, Wkf, bkf, Wvf, bvf, X3, Wc3, bc3);
  gemm3<<<dim3(32, 8, 3), 256, 0, stream>>>(X3, Wc3, bc3, QKV);
  attn_kernel<<<512, 512, 0, stream>>>(
      QKV, QKV + (size_t)MM * DD, QKV + (size_t)2 * MM * DD, mask, Wo, bo, out);
}

// Round 12
// 234.284 us; speedup vs baseline: 1.5058x; 1.0477x over previous
//
#include <hip/hip_runtime.h>
#include <stdint.h>

// Problem constants
#define MM 4096   // B*S
#define SS 1024   // S
#define DD 1024   // D
#define HH 16     // heads
#define DKK 64    // head dim

typedef __bf16 bf16x8 __attribute__((ext_vector_type(8)));
typedef __bf16 bf16x4 __attribute__((ext_vector_type(4)));
typedef float  f32x4  __attribute__((ext_vector_type(4)));

#define LOG2E 1.44269504088896340736f

__device__ __forceinline__ void gload_lds16(const void* g, void* l) {
  // async global->LDS, 16B per lane; LDS dest is wave-uniform base + lane*16
  __builtin_amdgcn_global_load_lds(
      (__attribute__((address_space(1))) void*)g,
      (__attribute__((address_space(3))) void*)l, 16, 0, 0);
}

// Swizzled element offset within a [rows][64] bf16 tile (row = 128B = 8 chunks
// of 16B). chunk' = chunk ^ (row&7) -> conflict-free ds_read_b128 column reads.
#define LSW(row, ch) ((row) * 64 + ((((ch) ^ ((row) & 7)) << 3)))

// ---------------- pass 0+1: cvt (6144 blocks) + wcombine (768 blocks) ------
// wcombine: Wc[z][h*64+j][i] = sum_d Wf_z[j][d] * W_z[h*64+d][i]
// block=(z,h,ic,jc): thread owns col i, acc[16] over j in [jc*16,jc*16+16).
// ALL acc loops fully unrolled -> static indices -> registers (rule #20).
__global__ __launch_bounds__(256) void prep(
    const float* __restrict__ q, const float* __restrict__ k,
    const float* __restrict__ v,
    const float* __restrict__ Wq, const float* __restrict__ bq,
    const float* __restrict__ Wk, const float* __restrict__ bk,
    const float* __restrict__ Wv, const float* __restrict__ bv,
    const float* __restrict__ Wqf, const float* __restrict__ bqf,
    const float* __restrict__ Wkf, const float* __restrict__ bkf,
    const float* __restrict__ Wvf, const float* __restrict__ bvf,
    __bf16* __restrict__ X3, __bf16* __restrict__ Wc3,
    float* __restrict__ bc3) {
  int blk = blockIdx.x;
  if (blk < 6144) {
    int z = blk >> 11;          // 0,1,2
    int bx = blk & 2047;
    const float* src = (z == 0) ? q : ((z == 1) ? k : v);
    size_t i = ((size_t)bx * 256 + threadIdx.x) * 8;
    float4 a = *(const float4*)(src + i);
    float4 b = *(const float4*)(src + i + 4);
    bf16x8 r;
    r[0] = (__bf16)a.x; r[1] = (__bf16)a.y; r[2] = (__bf16)a.z; r[3] = (__bf16)a.w;
    r[4] = (__bf16)b.x; r[5] = (__bf16)b.y; r[6] = (__bf16)b.z; r[7] = (__bf16)b.w;
    *(bf16x8*)(X3 + (size_t)z * MM * DD + i) = r;
  } else {
    int t = blk - 6144;          // [0,768): z(3) x h(16) x ic(4) x jc(4)
    int z = t >> 8;              // t/256
    int rem = t & 255;
    int h = rem >> 4, ic = (rem >> 2) & 3, jc = rem & 3;
    const float* W   = (z == 0) ? Wq  : ((z == 1) ? Wk  : Wv);
    const float* bs  = (z == 0) ? bq  : ((z == 1) ? bk  : bv);
    const float* Wf  = (z == 0) ? Wqf : ((z == 1) ? Wkf : Wvf);
    const float* bf_ = (z == 0) ? bqf : ((z == 1) ? bkf : bvf);
    int i = ic * 256 + threadIdx.x;
    const float* wfb = Wf + jc * 16 * DKK;   // 16 rows of Wf

    float acc[16];
#pragma unroll
    for (int jj = 0; jj < 16; ++jj) acc[jj] = 0.f;
#pragma unroll 4
    for (int d = 0; d < 64; ++d) {
      float wv = W[(size_t)(h * DKK + d) * DD + i];
#pragma unroll
      for (int jj = 0; jj < 16; ++jj)
        acc[jj] = fmaf(wfb[jj * DKK + d], wv, acc[jj]);  // uniform -> s_load
    }
#pragma unroll
    for (int jj = 0; jj < 16; ++jj)
      Wc3[(size_t)z * DD * DD + (size_t)(h * DKK + jc * 16 + jj) * DD + i] =
          (__bf16)acc[jj];

    if (ic == 0 && jc == 0 && threadIdx.x < 64) {
      int j = threadIdx.x;
      float bb = bf_[j];
      for (int d = 0; d < 64; ++d) bb += Wf[j * DKK + d] * bs[h * DKK + d];
      bc3[z * DD + h * DKK + j] = bb;
    }
  }
}

// ---------------- pass 2: fused 3x GEMM+bias+ReLU, C = relu(X@Wc^T + bc) ---
// z=0: Q rows [m][o];  z=1: K rows [m][o];  z=2: V stored TRANSPOSED
// per head: Vt[(bh*64+dk)*1024 + s]  (so attention PV reads are contiguous)
__global__ __launch_bounds__(256) void gemm3(const __bf16* __restrict__ X3,
                                             const __bf16* __restrict__ Wc3,
                                             const float* __restrict__ bc3,
                                             __bf16* __restrict__ QKV) {
  __shared__ __bf16 As[128 * 64];
  __shared__ __bf16 Bs[128 * 64];
  const int z = blockIdx.z;
  const __bf16* A  = X3  + (size_t)z * MM * DD;
  const __bf16* Bt = Wc3 + (size_t)z * DD * DD;
  const float* bias = bc3 + z * DD;
  __bf16* C = QKV + (size_t)z * MM * DD;

  const int tid = threadIdx.x;
  const int wave = tid >> 6, lane = tid & 63;
  const int l15 = lane & 15, l4 = lane >> 4;
  const int bm = blockIdx.x * 128;
  const int bn = blockIdx.y * 128;
  const int wr = (wave >> 1) * 64;
  const int wc = (wave & 1) * 64;

  f32x4 acc[4][4] = {};

  const int srow = wave * 8 + (lane >> 3);  // staging row within 32-row issue
  const int scol = (lane & 7) * 8;

  for (int kt = 0; kt < DD; kt += 64) {
    __syncthreads();
#pragma unroll
    for (int j = 0; j < 4; ++j) {
      int row = j * 32 + srow;
      gload_lds16(A  + (size_t)(bm + row) * DD + kt + scol, As + j * 2048 + wave * 512);
      gload_lds16(Bt + (size_t)(bn + row) * DD + kt + scol, Bs + j * 2048 + wave * 512);
    }
    asm volatile("s_waitcnt vmcnt(0)" ::: "memory");
    __syncthreads();
#pragma unroll
    for (int ks = 0; ks < 2; ++ks) {
      bf16x8 af[4], bfr[4];
#pragma unroll
      for (int mi = 0; mi < 4; ++mi)
        af[mi] = *(const bf16x8*)(As + (wr + mi * 16 + l15) * 64 + ks * 32 + l4 * 8);
#pragma unroll
      for (int ni = 0; ni < 4; ++ni)
        bfr[ni] = *(const bf16x8*)(Bs + (wc + ni * 16 + l15) * 64 + ks * 32 + l4 * 8);
#pragma unroll
      for (int mi = 0; mi < 4; ++mi)
#pragma unroll
        for (int ni = 0; ni < 4; ++ni)
          acc[mi][ni] = __builtin_amdgcn_mfma_f32_16x16x32_bf16(af[mi], bfr[ni], acc[mi][ni], 0, 0, 0);
    }
  }

  // epilogue: bias + relu + bf16 store (z==2 -> transposed per-head layout)
#pragma unroll
  for (int ni = 0; ni < 4; ++ni) {
    int n = bn + wc + ni * 16 + l15;
    float bb = bias[n];
#pragma unroll
    for (int mi = 0; mi < 4; ++mi) {
      if (z != 2) {
#pragma unroll
        for (int r = 0; r < 4; ++r) {
          int m = bm + wr + mi * 16 + l4 * 4 + r;
          float vv = acc[mi][ni][r] + bb;
          vv = vv > 0.f ? vv : 0.f;
          C[(size_t)m * DD + n] = (__bf16)vv;
        }
      } else {
        int m0 = bm + wr + mi * 16 + l4 * 4;
        int b = m0 >> 10, s0 = m0 & 1023;
        int h = n >> 6, dk = n & 63;
        bf16x4 pk;
#pragma unroll
        for (int r = 0; r < 4; ++r) {
          float vv = acc[mi][ni][r] + bb;
          vv = vv > 0.f ? vv : 0.f;
          pk[r] = (__bf16)vv;
        }
        *(bf16x4*)(C + ((size_t)(b * HH + h) * DKK + dk) * SS + s0) = pk;
      }
    }
  }
}

// ---------------- pass 3: flash attention + fused Wo epilogue --------------
// 512 blocks XCD-swizzled, 8 waves x 16 q rows. SWAPPED QK^T (S^T = K x Q):
// each lane owns ONE q row (l15) and all 64 keys -> in-lane softmax
// (15 fmax + 2 shfl instead of 32 shfl), packed b64 P-writes, transposed
// PV (O^T = V^T x P) and Wo epilogue. Mask as fminf-bias from LDS (exact
// replace semantics). DS ops/lane/tile ~50 -> ~10.
__global__ __launch_bounds__(512) void attn_kernel(
    const __bf16* __restrict__ Q,   // [4096][1024]
    const __bf16* __restrict__ K,   // [4096][1024]
    const __bf16* __restrict__ Vt,  // [64 bh][64 dk][1024 s]
    const int* __restrict__ mask,   // [64][1024]
    const float* __restrict__ Wo,   // [64][64]
    const float* __restrict__ bo,   // [64]
    float* __restrict__ out)        // [4][1024][1024]
{
  __shared__ __bf16 Qs[128 * 64];     // 16KB
  __shared__ __bf16 Ks[2][64 * 64];   // 16KB (double-buffered)
  __shared__ __bf16 Vs[2][64 * 64];   // 16KB
  __shared__ __bf16 Pw[8][16 * 64];   // 16KB per-wave P^T staging
  __shared__ __bf16 Wos[64 * 64];     // 8KB
  __shared__ float  Biasf[1024];      // 4KB  -> 76KB total, 2 blocks/CU

  const int tid = threadIdx.x;
  const int wave = tid >> 6, lane = tid & 63;
  const int l15 = lane & 15, l4 = lane >> 4;

  // T1: XCD remap. 512 blocks: XCD c gets bh [c*8,c*8+8) x all 8 qt.
  const int lin = blockIdx.x;
  const int swz = (lin & 7) * 64 + (lin >> 3);
  const int qt = swz & 7;
  const int bh = swz >> 3;
  const int b = bh >> 4, h = bh & 15;

  const __bf16* Qbase = Q + ((size_t)b * SS + qt * 128) * DD + h * 64;
  const __bf16* Kbase = K + (size_t)b * SS * DD + h * 64;
  const __bf16* Vbase = Vt + (size_t)bh * DKK * SS;

  // stage Wo -> LDS bf16, swizzled store
  for (int t = tid; t < 64 * 64; t += 512) {
    int row = t >> 6, col = t & 63;
    Wos[row * 64 + ((((col >> 3) ^ (row & 7)) << 3) | (col & 7))] = (__bf16)Wo[t];
  }
  // mask -> fminf bias: unmasked -> +1e30 (min keeps score), masked -> -10000
  // (in exp2 domain). fminf(s*SCL, bias) == exact "replace" semantics.
  for (int t = tid; t < 1024; t += 512)
    Biasf[t] = mask[bh * SS + t] ? 1e30f : (-10000.f * LOG2E);

  // staging map: lane l covers chunk (l&7) of row (..+ l>>3); row&7 == l>>3,
  // so pre-swizzled global chunk = (l&7)^(l>>3).   (rule #21: LDS stays linear)
  const int lr8 = lane >> 3;
  const int scol = (((lane & 7) ^ lr8) * 8);
  const int krow = wave * 8 + lr8;           // K/V stage row (64-row tile)

  // stage Q tile (128 rows): wave stages rows [wave*16, wave*16+16)
#pragma unroll
  for (int j = 0; j < 2; ++j)
    gload_lds16(Qbase + (size_t)(wave * 16 + j * 8 + lr8) * DD + scol,
                Qs + wave * 1024 + j * 512);
  // stage K/V tile 0 into buf 0
  gload_lds16(Kbase + (size_t)krow * DD + scol, Ks[0] + wave * 512);
  gload_lds16(Vbase + (size_t)krow * SS + scol, Vs[0] + wave * 512);
  asm volatile("s_waitcnt vmcnt(0)" ::: "memory");
  __syncthreads();

  // hoist this lane's Q fragments (B-operand rows = q = l15); Qs dead after
  bf16x8 aq[2];
#pragma unroll
  for (int ks = 0; ks < 2; ++ks)
    aq[ks] = *(const bf16x8*)(Qs + LSW(wave * 16 + l15, ks * 4 + l4));

  f32x4 o_acc[4] = {};              // O^T[dk = ni*16+l4*4+r][q = l15]
  float mrow = -1e30f, lrow = 0.f;  // scalar: this lane's q row
  const float SCL = 0.125f * LOG2E;

  // P^T-write swizzled element offset (row=q=l15, key/dk block per ni,l4)
  const int pwoff = l15 * 64;
  const int pwch0 = (l4 >> 1);        // chunk base adds 2*ni
  const int pwin  = (l4 & 1) << 2;    // inner b64 half

  for (int kt = 0; kt < SS / 64; ++kt) {
    const int cur = kt & 1;
    if (kt < SS / 64 - 1) {  // prefetch next K/V tile into other buffer
      gload_lds16(Kbase + (size_t)((kt + 1) * 64 + krow) * DD + scol,
                  Ks[cur ^ 1] + wave * 512);
      gload_lds16(Vbase + (size_t)krow * SS + (kt + 1) * 64 + scol,
                  Vs[cur ^ 1] + wave * 512);
    }

    // S^T = K Q^T : sc[ni][r] = S[q=l15][key = kt*64 + ni*16 + l4*4 + r]
    f32x4 sc[4] = {};
#pragma unroll
    for (int ks = 0; ks < 2; ++ks) {
#pragma unroll
      for (int ni = 0; ni < 4; ++ni) {
        bf16x8 kf = *(const bf16x8*)(Ks[cur] + LSW(ni * 16 + l15, ks * 4 + l4));
        sc[ni] = __builtin_amdgcn_mfma_f32_16x16x32_bf16(kf, aq[ks], sc[ni], 0, 0, 0);
      }
    }
    // scale + mask (fminf-bias, exact replace) in exp2 domain
#pragma unroll
    for (int ni = 0; ni < 4; ++ni) {
      float4 bb = *(const float4*)(Biasf + kt * 64 + ni * 16 + (l4 << 2));
      sc[ni][0] = fminf(sc[ni][0] * SCL, bb.x);
      sc[ni][1] = fminf(sc[ni][1] * SCL, bb.y);
      sc[ni][2] = fminf(sc[ni][2] * SCL, bb.z);
      sc[ni][3] = fminf(sc[ni][3] * SCL, bb.w);
    }
    // in-lane softmax over this lane's 16 keys + 2-shfl cross-l4 reduce
    float m = fmaxf(fmaxf(sc[0][0], sc[0][1]), fmaxf(sc[0][2], sc[0][3]));
#pragma unroll
    for (int ni = 1; ni < 4; ++ni)
      m = fmaxf(m, fmaxf(fmaxf(sc[ni][0], sc[ni][1]), fmaxf(sc[ni][2], sc[ni][3])));
    m = fmaxf(m, __shfl_xor(m, 16));
    m = fmaxf(m, __shfl_xor(m, 32));
    float mnew = fmaxf(mrow, m);
    float alpha = __builtin_exp2f(mrow - mnew);
    mrow = mnew;
    float s = 0.f;
#pragma unroll
    for (int ni = 0; ni < 4; ++ni)
#pragma unroll
      for (int r = 0; r < 4; ++r) {
        float p = __builtin_exp2f(sc[ni][r] - mnew);
        sc[ni][r] = p;
        s += p;
      }
    s += __shfl_xor(s, 16);
    s += __shfl_xor(s, 32);
    lrow = lrow * alpha + s;

    // P^T -> Pw (packed b64 writes, swizzled; 2-way conflict = free)
#pragma unroll
    for (int ni = 0; ni < 4; ++ni) {
      bf16x4 w;
      w[0] = (__bf16)sc[ni][0]; w[1] = (__bf16)sc[ni][1];
      w[2] = (__bf16)sc[ni][2]; w[3] = (__bf16)sc[ni][3];
      int ch = (2 * ni + pwch0) ^ (l15 & 7);
      *(bf16x4*)(&Pw[wave][pwoff + (ch << 3) + pwin]) = w;
    }
    asm volatile("" ::: "memory");
    // rescale O^T (skip when no row max changed anywhere in wave — T13)
    if (!__all(alpha == 1.0f)) {
#pragma unroll
      for (int ni = 0; ni < 4; ++ni)
#pragma unroll
        for (int r = 0; r < 4; ++r) o_acc[ni][r] *= alpha;
    }
    // O^T += V^T P : A = V^T[dk][key], B = P[q][key]
#pragma unroll
    for (int ks = 0; ks < 2; ++ks) {
      bf16x8 ap = *(const bf16x8*)(&Pw[wave][LSW(l15, ks * 4 + l4)]);
#pragma unroll
      for (int ni = 0; ni < 4; ++ni) {
        bf16x8 vf = *(const bf16x8*)(Vs[cur] + LSW(ni * 16 + l15, ks * 4 + l4));
        o_acc[ni] = __builtin_amdgcn_mfma_f32_16x16x32_bf16(vf, ap, o_acc[ni], 0, 0, 0);
      }
    }
    // drain prefetch + protect buf cur (overwritten next iter)
    asm volatile("s_waitcnt vmcnt(0)" ::: "memory");
    __syncthreads();
  }

  // normalize O^T, stage to Pw, fused Wo: final^T[j][q] = Wo x (O/l)
  float rinv = 1.0f / lrow;
#pragma unroll
  for (int ni = 0; ni < 4; ++ni) {
    bf16x4 w;
    w[0] = (__bf16)(o_acc[ni][0] * rinv); w[1] = (__bf16)(o_acc[ni][1] * rinv);
    w[2] = (__bf16)(o_acc[ni][2] * rinv); w[3] = (__bf16)(o_acc[ni][3] * rinv);
    int ch = (2 * ni + pwch0) ^ (l15 & 7);
    *(bf16x4*)(&Pw[wave][pwoff + (ch << 3) + pwin]) = w;
  }
  asm volatile("" ::: "memory");
  f32x4 facc[4] = {};
#pragma unroll
  for (int ks = 0; ks < 2; ++ks) {
    bf16x8 ao = *(const bf16x8*)(&Pw[wave][LSW(l15, ks * 4 + l4)]);
#pragma unroll
    for (int ni = 0; ni < 4; ++ni) {
      bf16x8 wf = *(const bf16x8*)(Wos + LSW(ni * 16 + l15, ks * 4 + l4));
      facc[ni] = __builtin_amdgcn_mfma_f32_16x16x32_bf16(wf, ao, facc[ni], 0, 0, 0);
    }
  }
  // store: lane's q row = l15; j block = ni*16 + l4*4 (+r) -> float4 stores
  const int qrow = qt * 128 + wave * 16 + l15;
  float* orow = out + ((size_t)b * SS + qrow) * DD + h * 64;
#pragma unroll
  for (int ni = 0; ni < 4; ++ni) {
    int j0 = ni * 16 + (l4 << 2);
    float4 bov = *(const float4*)(bo + j0);
    float4 ov;
    ov.x = facc[ni][0] + bov.x; ov.y = facc[ni][1] + bov.y;
    ov.z = facc[ni][2] + bov.z; ov.w = facc[ni][3] + bov.w;
    *(float4*)(orow + j0) = ov;
  }
}

// ---------------- host ----------------
extern "C" void kernel_launch(void* const* d_in, const int* in_sizes, int n_in,
                              void* d_out, int out_size, void* d_ws, size_t ws_size,
                              hipStream_t stream) {
  const float* q   = (const float*)d_in[0];
  const float* k   = (const float*)d_in[1];
  const float* v   = (const float*)d_in[2];
  const int*   mask= (const int*)d_in[3];
  const float* Wq  = (const float*)d_in[4];
  const float* bq  = (const float*)d_in[5];
  const float* Wk  = (const float*)d_in[6];
  const float* bk  = (const float*)d_in[7];
  const float* Wv  = (const float*)d_in[8];
  const float* bv  = (const float*)d_in[9];
  const float* Wqf = (const float*)d_in[10];
  const float* bqf = (const float*)d_in[11];
  const float* Wkf = (const float*)d_in[12];
  const float* bkf = (const float*)d_in[13];
  const float* Wvf = (const float*)d_in[14];
  const float* bvf = (const float*)d_in[15];
  const float* Wo  = (const float*)d_in[16];
  const float* bo  = (const float*)d_in[17];
  float* out = (float*)d_out;

  // workspace layout
  char* p = (char*)d_ws;
  __bf16* X3  = (__bf16*)p; p += (size_t)3 * MM * DD * 2;   // 24 MB
  __bf16* Wc3 = (__bf16*)p; p += (size_t)3 * DD * DD * 2;   // 6 MB
  __bf16* QKV = (__bf16*)p; p += (size_t)3 * MM * DD * 2;   // 24 MB
  float*  bc3 = (float*)p;  p += (size_t)3 * DD * 4;        // 12 KB
  if ((size_t)(p - (char*)d_ws) > ws_size) return;  // workspace too small

  prep<<<6912, 256, 0, stream>>>(q, k, v, Wq, bq, Wk, bk, Wv, bv,
                                 Wqf, bqf, Wkf, bkf, Wvf, bvf, X3, Wc3, bc3);
  gemm3<<<dim3(32, 8, 3), 256, 0, stream>>>(X3, Wc3, bc3, QKV);
  attn_kernel<<<512, 512, 0, stream>>>(
      QKV, QKV + (size_t)MM * DD, QKV + (size_t)2 * MM * DD, mask, Wo, bo, out);
}